// Round 6
// baseline (594.243 us; speedup 1.0000x reference)
//
#include <hip/hip_runtime.h>
#include <hip/hip_bf16.h>
#include <float.h>

// Problem constants: B=4, S=2048, D=1024, C=16384, k=8
#define R_TOTAL 8192
#define D_DIM   1024
#define C_TOTAL 16384
#define KSEL    8
#define XN  ((size_t)R_TOTAL * D_DIM)   // 8,388,608
#define CBN ((size_t)C_TOTAL * D_DIM)   // 16,777,216
#define NSPLIT  8
#define SEGC    (C_TOTAL / NSPLIT)      // 2048 codes per segment (per block)
#define NCHUNK  (SEGC / 256)            // 8 chunks of 256 codes
#define NKT     (NCHUNK * 16)           // 128 K-tiles (BK=64) per block
#define NC_RES  24                      // candidates exact-rescored per row

typedef __attribute__((ext_vector_type(8)))  short short8v;   // 8 bf16
typedef __attribute__((ext_vector_type(16))) float f32x16;
typedef __attribute__((ext_vector_type(8)))  unsigned short ushort8;

__device__ __forceinline__ unsigned short f2bf(float f) {  // RNE f32->bf16
  unsigned u = __float_as_uint(f);
  u = (u + 0x7fffu + ((u >> 16) & 1u)) >> 16;
  return (unsigned short)u;
}

__device__ __forceinline__ void gload_lds16(const void* g, void* l) {
  __builtin_amdgcn_global_load_lds((const __attribute__((address_space(1))) void*)g,
                                   (__attribute__((address_space(3))) void*)l, 16, 0, 0);
}

// ---------------------------------------------------------------------------
// Kernel 0: f32 -> bf16 conversion of X and CB
// ---------------------------------------------------------------------------
__global__ void cvt_kernel(const float* __restrict__ X, const float* __restrict__ CB,
                           unsigned short* __restrict__ Xb, unsigned short* __restrict__ CBb) {
  size_t e = ((size_t)blockIdx.x * 256 + threadIdx.x) * 8;
  const float* src; unsigned short* dst; size_t off;
  if (e < XN) { src = X;  dst = Xb;  off = e; }
  else        { src = CB; dst = CBb; off = e - XN; }
  float4 v0 = *(const float4*)(src + off);
  float4 v1 = *(const float4*)(src + off + 4);
  ushort8 o;
  o[0]=f2bf(v0.x); o[1]=f2bf(v0.y); o[2]=f2bf(v0.z); o[3]=f2bf(v0.w);
  o[4]=f2bf(v1.x); o[5]=f2bf(v1.y); o[6]=f2bf(v1.z); o[7]=f2bf(v1.w);
  *(ushort8*)(dst + off) = o;
}

// ---------------------------------------------------------------------------
// Kernel 1: c2[c] = sum_d CB[c][d]^2 (f32 exact, one wave per code)
// ---------------------------------------------------------------------------
__global__ void c2_kernel(const float* __restrict__ cb, float* __restrict__ c2) {
  const int wave = threadIdx.x >> 6;
  const int lane = threadIdx.x & 63;
  const int code = blockIdx.x * 4 + wave;
  const float* row = cb + (size_t)code * D_DIM;
  float s = 0.f;
  #pragma unroll
  for (int i = 0; i < D_DIM / 64; ++i) { float v = row[lane + i * 64]; s += v * v; }
  #pragma unroll
  for (int off = 32; off >= 1; off >>= 1) s += __shfl_xor(s, off, 64);
  if (lane == 0) c2[code] = s;
}

// ---------------------------------------------------------------------------
// Kernel 2: bf16 MFMA GEMM (S^T: 256 codes x 256 xrows tile) with fused
// per-xrow approximate top-8 per 2048-code segment.
// 512 thr = 8 waves (2 code-halves x 4 xrow-quarters); per wave 128x64 out
// via mfma_f32_32x32x16_bf16: acc[fm=4][fn=2] f32x16.
//
// ROUND-6 SCHEDULE: one-phase-ahead fragment pipeline (m201 mechanism).
// Two named frag sets E/O alternate; phase p's MFMAs consume frags issued in
// phase p-1, so LDS queue drains UNDER the previous MFMA cluster and the
// compiler's pre-MFMA lgkmcnt is counted (leaves next-phase reads in
// flight). Per tile (BK=64, 4 K-slices):
//   p0: read O(ks1); STAGE_A(g+1); bar; MFMA(E)
//   p1: read E(ks2); STAGE_X(g+1); bar; MFMA(O)
//   p2: read O(ks3);               bar; MFMA(E)
//   p3: vmcnt(0) [stage loads 2-3 phases old]; bar; read E(ks0 of g+1,
//       other buffer - now fully written by ALL waves); MFMA(O)
// vmcnt never drains fresh loads; lgkmcnt never fully drains (compiler
// scoreboard). sched_barrier(0) after each MFMA cluster pins phase shape.
//
// Swizzle: rows [*][64] bf16 (128B), kbyte ^= ((row&7)<<4), applied on the
// global source (linear gload_lds dest) + on ds_read addrs (both-sides, #21).
// ---------------------------------------------------------------------------
__global__ __launch_bounds__(512, 2)
void gemm_topk_kernel(const unsigned short* __restrict__ Xb,
                      const unsigned short* __restrict__ CBb,
                      const float* __restrict__ c2g,
                      float* __restrict__ pval, int* __restrict__ pid) {
  extern __shared__ char smem[];
  float* c2s = (float*)(smem + 131072);

  const int t   = threadIdx.x;
  const int wid = t >> 6, l = t & 63;
  const int wr  = wid >> 2;          // 0..1: code half (128 rows)
  const int wc  = wid & 3;           // 0..3: xrow quarter (64 cols)
  const int l31 = l & 31, hi = l >> 5;

  const int xt    = blockIdx.x & 31;        // 32 xrow tiles
  const int seg   = blockIdx.x >> 5;        // 8 segments
  const int xbase = xt * 256;
  const int cb0   = seg * SEGC;

  // preload segment c2 into LDS (512 thr x float4 = 2048 f32)
  *(float4*)&c2s[t * 4] = *(const float4*)(c2g + cb0 + t * 4);

  // staging: issue i covers rows i*64+(t>>3); 16B col chunk (t&7), swizzled src
  const int srow = t >> 3;
  const int sswz = (((t & 7) * 16) ^ ((srow & 7) << 4)) >> 1;  // elem offset
  const int fswz = (l & 7) << 4;                                // read swizzle

  f32x16 acc[4][2];
  float tv[2][KSEL]; int ti[2][KSEL];
  #pragma unroll
  for (int fm = 0; fm < 4; ++fm)
    #pragma unroll
    for (int fn = 0; fn < 2; ++fn)
      #pragma unroll
      for (int r = 0; r < 16; ++r) acc[fm][fn][r] = 0.f;
  #pragma unroll
  for (int fn = 0; fn < 2; ++fn)
    #pragma unroll
    for (int q = 0; q < KSEL; ++q) { tv[fn][q] = -FLT_MAX; ti[fn][q] = 0; }

  auto STAGE_A = [&](int g) {   // 4 loads: codes half-tiles of K-tile g
    const int kbase = (g & 15) * 64;
    const int arow0 = cb0 + (g >> 4) * 256;
    char* As = smem + (g & 1) * 32768;
    #pragma unroll
    for (int i = 0; i < 4; ++i)
      gload_lds16(CBb + (size_t)(arow0 + i * 64 + srow) * D_DIM + kbase + sswz,
                  As + (i * 512 + t) * 16);
  };
  auto STAGE_X = [&](int g) {   // 4 loads: xrow half-tiles of K-tile g
    const int kbase = (g & 15) * 64;
    char* Xs = smem + 65536 + (g & 1) * 32768;
    #pragma unroll
    for (int i = 0; i < 4; ++i)
      gload_lds16(Xb + (size_t)(xbase + i * 64 + srow) * D_DIM + kbase + sswz,
                  Xs + (i * 512 + t) * 16);
  };

  // two named fragment sets (static indexing only - rule 20)
  short8v avE[4], bvE[2], avO[4], bvO[2];

#define READ_FRAGS(AV, BV, ABUF, XBUF, P)                                       \
  {                                                                             \
    const int kb_ = ((P) * 32 + hi * 16) ^ fswz;                                \
    _Pragma("unroll")                                                           \
    for (int fm_ = 0; fm_ < 4; ++fm_)                                           \
      AV[fm_] = *(const short8v*)((ABUF) +                                      \
                    (wr * 128 + fm_ * 32 + l31) * 128 + kb_);                   \
    _Pragma("unroll")                                                           \
    for (int fn_ = 0; fn_ < 2; ++fn_)                                           \
      BV[fn_] = *(const short8v*)((XBUF) +                                      \
                    (wc * 64 + fn_ * 32 + l31) * 128 + kb_);                    \
  }

#define MFMA8(AV, BV)                                                           \
  {                                                                             \
    __builtin_amdgcn_s_setprio(1);                                              \
    _Pragma("unroll")                                                           \
    for (int fm_ = 0; fm_ < 4; ++fm_)                                           \
      _Pragma("unroll")                                                         \
      for (int fn_ = 0; fn_ < 2; ++fn_)                                         \
        acc[fm_][fn_] = __builtin_amdgcn_mfma_f32_32x32x16_bf16(                \
            AV[fm_], BV[fn_], acc[fm_][fn_], 0, 0, 0);                          \
    __builtin_amdgcn_s_setprio(0);                                              \
    __builtin_amdgcn_sched_barrier(0);                                          \
  }

  // ---- prologue: stage tile 0, drain, pre-read ks0 frags ----
  STAGE_A(0); STAGE_X(0);
  asm volatile("s_waitcnt vmcnt(0) lgkmcnt(0)" ::: "memory");
  __builtin_amdgcn_s_barrier();
  __builtin_amdgcn_sched_barrier(0);
  READ_FRAGS(avE, bvE, (const char*)smem, (const char*)smem + 65536, 0);

  for (int g = 0; g < NKT; ++g) {
    const char* As  = smem + (g & 1) * 32768;
    const char* Xs  = smem + 65536 + (g & 1) * 32768;
    const char* Asn = smem + ((g + 1) & 1) * 32768;
    const char* Xsn = smem + 65536 + ((g + 1) & 1) * 32768;
    const bool more = (g + 1 < NKT);

    // --- p0: consume E(ks0), issue O(ks1), stage A(g+1) ---
    READ_FRAGS(avO, bvO, As, Xs, 1);
    if (more) STAGE_A(g + 1);
    __builtin_amdgcn_s_barrier();
    MFMA8(avE, bvE);

    // --- p1: consume O(ks1), issue E(ks2), stage X(g+1) ---
    READ_FRAGS(avE, bvE, As, Xs, 2);
    if (more) STAGE_X(g + 1);
    __builtin_amdgcn_s_barrier();
    MFMA8(avO, bvO);

    // --- p2: consume E(ks2), issue O(ks3) ---
    READ_FRAGS(avO, bvO, As, Xs, 3);
    __builtin_amdgcn_s_barrier();
    MFMA8(avE, bvE);

    // --- p3: consume O(ks3), pre-read E(ks0 of g+1) from other buffer ---
    asm volatile("s_waitcnt vmcnt(0)" ::: "memory");  // stage g+1: 2-3 phases old
    __builtin_amdgcn_s_barrier();                      // ALL waves' stages landed
    __builtin_amdgcn_sched_barrier(0);
    if (more) READ_FRAGS(avE, bvE, Asn, Xsn, 0);
    MFMA8(avO, bvO);

    if ((g & 15) == 15) {
      // -------- selection epilogue for chunk ch (registers + c2s only) -----
      const int ch = g >> 4;
      #pragma unroll
      for (int fm = 0; fm < 4; ++fm) {
        const int rloc = ch * 256 + wr * 128 + fm * 32 + hi * 4;
        const int idb  = cb0 + ch * 256 + wr * 128 + fm * 32 + hi * 4;
        #pragma unroll
        for (int q = 0; q < 4; ++q) {
          const float4 cq = *(const float4*)&c2s[rloc + q * 8];
          #pragma unroll
          for (int fn = 0; fn < 2; ++fn) {
            #pragma unroll
            for (int r = 0; r < 4; ++r) {
              const float c2v = (r == 0) ? cq.x : (r == 1) ? cq.y : (r == 2) ? cq.z : cq.w;
              const float s = 2.f * acc[fm][fn][q * 4 + r] - c2v;
              if (s > tv[fn][KSEL - 1]) {      // strict >: ids scanned ascending
                float cv = s; int ci = idb + q * 8 + r;
                #pragma unroll
                for (int q2 = 0; q2 < KSEL; ++q2) {
                  if (cv > tv[fn][q2]) {
                    const float t0 = tv[fn][q2]; tv[fn][q2] = cv; cv = t0;
                    const int   t1 = ti[fn][q2]; ti[fn][q2] = ci; ci = t1;
                  }
                }
              }
            }
          }
        }
      }
      #pragma unroll
      for (int fm = 0; fm < 4; ++fm)
        #pragma unroll
        for (int fn = 0; fn < 2; ++fn)
          #pragma unroll
          for (int r = 0; r < 16; ++r) acc[fm][fn][r] = 0.f;
    }
  }

#undef READ_FRAGS
#undef MFMA8

  // -------- merge 4 lane-lists per xrow, write per-segment top-8 --------
  asm volatile("s_waitcnt vmcnt(0) lgkmcnt(0)" ::: "memory");
  __builtin_amdgcn_s_barrier();
  float* mv = (float*)smem;            // [256 xrows][4 lists][8] = 32KB
  int*   mi = (int*)(smem + 32768);
  #pragma unroll
  for (int fn = 0; fn < 2; ++fn) {
    const int xrL = wc * 64 + fn * 32 + l31;
    const int li  = wr * 2 + hi;
    #pragma unroll
    for (int q = 0; q < KSEL; ++q) {
      mv[xrL * 32 + li * 8 + q] = tv[fn][q];
      mi[xrL * 32 + li * 8 + q] = ti[fn][q];
    }
  }
  __syncthreads();
  if (t < 256) {
    float bvv[KSEL]; int bii[KSEL];
    #pragma unroll
    for (int q = 0; q < KSEL; ++q) { bvv[q] = -FLT_MAX; bii[q] = 0x7fffffff; }
    for (int c = 0; c < 32; ++c) {
      float cv = mv[t * 32 + c]; int ci = mi[t * 32 + c];
      if (cv > bvv[KSEL - 1] || (cv == bvv[KSEL - 1] && ci < bii[KSEL - 1])) {
        #pragma unroll
        for (int q = 0; q < KSEL; ++q) {
          if (cv > bvv[q] || (cv == bvv[q] && ci < bii[q])) {
            const float t0 = bvv[q]; bvv[q] = cv; cv = t0;
            const int   t1 = bii[q]; bii[q] = ci; ci = t1;
          }
        }
      }
    }
    const size_t base = ((size_t)(xbase + t) * NSPLIT + seg) * KSEL;
    #pragma unroll
    for (int q = 0; q < KSEL; ++q) { pval[base + q] = bvv[q]; pid[base + q] = bii[q]; }
  }
}

// ---------------------------------------------------------------------------
// Kernel 3: per row: merge 64 approx candidates -> top-24, exact f32 rescore
// of those 24, final top-8 (ties: lower id), gather + average.
// ---------------------------------------------------------------------------
__global__ __launch_bounds__(256)
void rescore_kernel(const float* __restrict__ X, const float* __restrict__ CB,
                    const float* __restrict__ c2g,
                    const float* __restrict__ pval, const int* __restrict__ pid,
                    float* __restrict__ out, float* __restrict__ out_ids, int nsplit) {
  const int row = blockIdx.x;
  const int t = threadIdx.x;
  __shared__ float xs[D_DIM];
  __shared__ int   scid[NC_RES];
  __shared__ float sv[NC_RES];
  __shared__ int   topid[KSEL];

  *(float4*)&xs[t * 4] = *(const float4*)(X + (size_t)row * D_DIM + t * 4);

  const int ncand = nsplit * KSEL;          // 64
  const int NC = NC_RES < ncand ? NC_RES : ncand;

  if (t < 64) {   // wave 0: merge candidates by approx score -> top-NC ids
    float v = -FLT_MAX; int idv = 0x7fffffff;
    if (t < ncand) {
      v   = pval[(size_t)row * ncand + t];
      idv = pid[(size_t)row * ncand + t];
    }
    for (int it = 0; it < NC; ++it) {
      float bv = v; int bid = idv;
      #pragma unroll
      for (int off = 32; off >= 1; off >>= 1) {
        float ov = __shfl_xor(bv, off, 64);
        int   oi = __shfl_xor(bid, off, 64);
        if (ov > bv || (ov == bv && oi < bid)) { bv = ov; bid = oi; }
      }
      if (t == 0) scid[it] = bid;
      if (idv == bid) v = -FLT_MAX;   // remove winner (ids unique)
    }
  }
  __syncthreads();

  const int w = t >> 6, ln = t & 63;
  for (int c = w; c < NC; c += 4) {
    const int id = scid[c];
    const float* cr = CB + (size_t)id * D_DIM;
    float s = 0.f;
    #pragma unroll
    for (int i = 0; i < 4; ++i) {
      const float4 cv = *(const float4*)(cr + ln * 4 + i * 256);
      const float4 xv = *(const float4*)&xs[ln * 4 + i * 256];
      s += cv.x * xv.x + cv.y * xv.y + cv.z * xv.z + cv.w * xv.w;
    }
    #pragma unroll
    for (int off = 32; off >= 1; off >>= 1) s += __shfl_xor(s, off, 64);
    if (ln == 0) sv[c] = 2.f * s - c2g[id];
  }
  __syncthreads();

  if (t == 0) {
    float bv[KSEL]; int bi[KSEL];
    #pragma unroll
    for (int q = 0; q < KSEL; ++q) { bv[q] = -FLT_MAX; bi[q] = 0x7fffffff; }
    for (int c = 0; c < NC; ++c) {
      float cv = sv[c]; int ci = scid[c];
      #pragma unroll
      for (int q = 0; q < KSEL; ++q) {
        if (cv > bv[q] || (cv == bv[q] && ci < bi[q])) {
          const float t0 = bv[q]; bv[q] = cv; cv = t0;
          const int   t1 = bi[q]; bi[q] = ci; ci = t1;
        }
      }
    }
    #pragma unroll
    for (int q = 0; q < KSEL; ++q) {
      topid[q] = bi[q];
      out_ids[(size_t)row * KSEL + q] = (float)bi[q];
    }
  }
  __syncthreads();

  float4 a = {0.f, 0.f, 0.f, 0.f};
  #pragma unroll
  for (int q = 0; q < KSEL; ++q) {
    const float4 cv = *(const float4*)(CB + (size_t)topid[q] * D_DIM + t * 4);
    a.x += cv.x; a.y += cv.y; a.z += cv.z; a.w += cv.w;
  }
  a.x *= 0.125f; a.y *= 0.125f; a.z *= 0.125f; a.w *= 0.125f;
  *(float4*)(out + (size_t)row * D_DIM + t * 4) = a;
}

// ---------------------------------------------------------------------------
extern "C" void kernel_launch(void* const* d_in, const int* in_sizes, int n_in,
                              void* d_out, int out_size, void* d_ws, size_t ws_size,
                              hipStream_t stream) {
  const float* X  = (const float*)d_in[0];
  const float* CB = (const float*)d_in[1];
  // d_in[2] = kcodes, fixed at 8 (compiled in)

  float* out     = (float*)d_out;
  float* out_ids = out + XN;

  const size_t XbB  = XN * 2;        // 16 MB
  const size_t CBbB = CBN * 2;       // 32 MB
  const size_t c2B  = C_TOTAL * 4;   // 64 KB
  const size_t pvB  = (size_t)R_TOTAL * NSPLIT * KSEL * 4;  // 2 MB

  char* p = (char*)d_ws;
  unsigned short* Xb;
  unsigned short* CBb;
  if (ws_size >= XbB + CBbB + c2B + 2 * pvB) {
    Xb  = (unsigned short*)p; p += XbB;
    CBb = (unsigned short*)p; p += CBbB;
  } else {
    // CB bf16 lives in d_out's outputs region (overwritten at the very end)
    CBb = (unsigned short*)d_out;
    Xb  = (unsigned short*)p; p += XbB;
  }
  float* c2   = (float*)p; p += c2B;
  float* pval = (float*)p; p += pvB;
  int*   pid  = (int*)p;

  hipLaunchKernelGGL(cvt_kernel, dim3((unsigned)((XN + CBN) / 8 / 256)), dim3(256), 0, stream,
                     X, CB, Xb, CBb);
  hipLaunchKernelGGL(c2_kernel, dim3(C_TOTAL / 4), dim3(256), 0, stream, CB, c2);
  hipLaunchKernelGGL(gemm_topk_kernel, dim3(32 * NSPLIT), dim3(512), 136 * 1024, stream,
                     Xb, CBb, c2, pval, pid);
  hipLaunchKernelGGL(rescore_kernel, dim3(R_TOTAL), dim3(256), 0, stream,
                     X, CB, c2, pval, pid, out, out_ids, NSPLIT);
}

// Round 7
// 591.879 us; speedup vs baseline: 1.0040x; 1.0040x over previous
//
#include <hip/hip_runtime.h>
#include <hip/hip_bf16.h>
#include <float.h>

// Problem constants: B=4, S=2048, D=1024, C=16384, k=8
#define R_TOTAL 8192
#define D_DIM   1024
#define C_TOTAL 16384
#define KSEL    8
#define XN  ((size_t)R_TOTAL * D_DIM)   // 8,388,608
#define CBN ((size_t)C_TOTAL * D_DIM)   // 16,777,216
#define NSPLIT  8
#define SEGC    (C_TOTAL / NSPLIT)      // 2048 codes per segment (per block)
#define NCHUNK  (SEGC / 256)            // 8 chunks of 256 codes
#define NKT     (NCHUNK * 16)           // 128 K-tiles (BK=64) per block
#define NC_RES  24                      // candidates exact-rescored per row

typedef __attribute__((ext_vector_type(8)))  short short8v;   // 8 bf16
typedef __attribute__((ext_vector_type(16))) float f32x16;
typedef __attribute__((ext_vector_type(8)))  unsigned short ushort8;

__device__ __forceinline__ unsigned short f2bf(float f) {  // RNE f32->bf16
  unsigned u = __float_as_uint(f);
  u = (u + 0x7fffu + ((u >> 16) & 1u)) >> 16;
  return (unsigned short)u;
}

__device__ __forceinline__ void gload_lds16(const void* g, void* l) {
  __builtin_amdgcn_global_load_lds((const __attribute__((address_space(1))) void*)g,
                                   (__attribute__((address_space(3))) void*)l, 16, 0, 0);
}

// ---------------------------------------------------------------------------
// Kernel 0: f32 -> bf16 conversion of X and CB
// ---------------------------------------------------------------------------
__global__ void cvt_kernel(const float* __restrict__ X, const float* __restrict__ CB,
                           unsigned short* __restrict__ Xb, unsigned short* __restrict__ CBb) {
  size_t e = ((size_t)blockIdx.x * 256 + threadIdx.x) * 8;
  const float* src; unsigned short* dst; size_t off;
  if (e < XN) { src = X;  dst = Xb;  off = e; }
  else        { src = CB; dst = CBb; off = e - XN; }
  float4 v0 = *(const float4*)(src + off);
  float4 v1 = *(const float4*)(src + off + 4);
  ushort8 o;
  o[0]=f2bf(v0.x); o[1]=f2bf(v0.y); o[2]=f2bf(v0.z); o[3]=f2bf(v0.w);
  o[4]=f2bf(v1.x); o[5]=f2bf(v1.y); o[6]=f2bf(v1.z); o[7]=f2bf(v1.w);
  *(ushort8*)(dst + off) = o;
}

// ---------------------------------------------------------------------------
// Kernel 1: c2[c] = sum_d CB[c][d]^2 (f32 exact, one wave per code)
// ---------------------------------------------------------------------------
__global__ void c2_kernel(const float* __restrict__ cb, float* __restrict__ c2) {
  const int wave = threadIdx.x >> 6;
  const int lane = threadIdx.x & 63;
  const int code = blockIdx.x * 4 + wave;
  const float* row = cb + (size_t)code * D_DIM;
  float s = 0.f;
  #pragma unroll
  for (int i = 0; i < D_DIM / 64; ++i) { float v = row[lane + i * 64]; s += v * v; }
  #pragma unroll
  for (int off = 32; off >= 1; off >>= 1) s += __shfl_xor(s, off, 64);
  if (lane == 0) c2[code] = s;
}

// ---------------------------------------------------------------------------
// Kernel 2: bf16 MFMA GEMM (S^T: 256 codes x 256 xrows tile) with fused
// per-xrow approximate top-8 per 2048-code segment.
// 512 thr = 8 waves (2 code-halves x 4 xrow-quarters); per wave 128x64 out
// via mfma_f32_32x32x16_bf16: acc[fm=4][fn=2] f32x16.
//
// ROUND-7 SCHEDULE (r5 counted-vmcnt + r6 read-ahead, merged):
//   tile g: STAGE_A(g+1)                 [before the wait - r5 trick]
//           vmcnt(4)                     [A(g),X(g) landed; A(g+1) in flight]
//           barrier#1
//           READ E(ks0)                  [single exposed-latency point/tile]
//           READ O(ks1); STAGE_X(g+1); MFMA8(E)
//           READ E(ks2);                 MFMA8(O)
//           READ O(ks3);                 MFMA8(E)
//                                        MFMA8(O)
//           [chunk boundary: register-only selection epilogue]
//           barrier#2                    [reads of buf g done before g+2 stage]
// NO vmcnt(0) in the loop; NO intra-tile barriers; 2 barriers/K-tile.
// Compiler's precise lgkmcnt scoreboard orders each MFMA cluster on the
// one-phase-old reads; sched_barrier(0) pins cluster boundaries.
// Hazards: STAGE_*(g+1) writes buf (g+1)&1, whose prior readers (tile g-1)
// all passed barrier#2(g-1) before these issue. vmcnt(4) at tile g+1 top
// waits A(g+1)+X(g+1) (issued ~3-4 phases = ~2000cyc earlier > HBM 900cyc).
//
// Swizzle: rows [*][64] bf16 (128B), kbyte ^= ((row&7)<<4), applied on the
// global source (linear gload_lds dest) + on ds_read addrs (both-sides, #21).
// Main-loop reads are bank-conflict-free (slots c^(l&7) distinct per 8-lane
// group); the r3-r6 SQ_LDS_BANK_CONFLICT=3.3e7 was the END MERGE's 128B-
// stride access (fixed below with stride-33 padding).
// ---------------------------------------------------------------------------
__global__ __launch_bounds__(512, 2)
void gemm_topk_kernel(const unsigned short* __restrict__ Xb,
                      const unsigned short* __restrict__ CBb,
                      const float* __restrict__ c2g,
                      float* __restrict__ pval, int* __restrict__ pid) {
  extern __shared__ char smem[];
  float* c2s = (float*)(smem + 131072);

  const int t   = threadIdx.x;
  const int wid = t >> 6, l = t & 63;
  const int wr  = wid >> 2;          // 0..1: code half (128 rows)
  const int wc  = wid & 3;           // 0..3: xrow quarter (64 cols)
  const int l31 = l & 31, hi = l >> 5;

  const int xt    = blockIdx.x & 31;        // 32 xrow tiles
  const int seg   = blockIdx.x >> 5;        // 8 segments
  const int xbase = xt * 256;
  const int cb0   = seg * SEGC;

  // preload segment c2 into LDS (512 thr x float4 = 2048 f32)
  *(float4*)&c2s[t * 4] = *(const float4*)(c2g + cb0 + t * 4);

  // staging: issue i covers rows i*64+(t>>3); 16B col chunk (t&7), swizzled src
  const int srow = t >> 3;
  const int sswz = (((t & 7) * 16) ^ ((srow & 7) << 4)) >> 1;  // elem offset
  const int fswz = (l & 7) << 4;                                // read swizzle

  f32x16 acc[4][2];
  float tv[2][KSEL]; int ti[2][KSEL];
  #pragma unroll
  for (int fm = 0; fm < 4; ++fm)
    #pragma unroll
    for (int fn = 0; fn < 2; ++fn)
      #pragma unroll
      for (int r = 0; r < 16; ++r) acc[fm][fn][r] = 0.f;
  #pragma unroll
  for (int fn = 0; fn < 2; ++fn)
    #pragma unroll
    for (int q = 0; q < KSEL; ++q) { tv[fn][q] = -FLT_MAX; ti[fn][q] = 0; }

  auto STAGE_A = [&](int g) {   // 4 loads: codes half-tiles of K-tile g
    const int kbase = (g & 15) * 64;
    const int arow0 = cb0 + (g >> 4) * 256;
    char* As = smem + (g & 1) * 32768;
    #pragma unroll
    for (int i = 0; i < 4; ++i)
      gload_lds16(CBb + (size_t)(arow0 + i * 64 + srow) * D_DIM + kbase + sswz,
                  As + (i * 512 + t) * 16);
  };
  auto STAGE_X = [&](int g) {   // 4 loads: xrow half-tiles of K-tile g
    const int kbase = (g & 15) * 64;
    char* Xs = smem + 65536 + (g & 1) * 32768;
    #pragma unroll
    for (int i = 0; i < 4; ++i)
      gload_lds16(Xb + (size_t)(xbase + i * 64 + srow) * D_DIM + kbase + sswz,
                  Xs + (i * 512 + t) * 16);
  };

  // two named fragment sets (static indexing only - rule 20)
  short8v avE[4], bvE[2], avO[4], bvO[2];

#define READ_FRAGS(AV, BV, ABUF, XBUF, P)                                       \
  {                                                                             \
    const int kb_ = ((P) * 32 + hi * 16) ^ fswz;                                \
    _Pragma("unroll")                                                           \
    for (int fm_ = 0; fm_ < 4; ++fm_)                                           \
      AV[fm_] = *(const short8v*)((ABUF) +                                      \
                    (wr * 128 + fm_ * 32 + l31) * 128 + kb_);                   \
    _Pragma("unroll")                                                           \
    for (int fn_ = 0; fn_ < 2; ++fn_)                                           \
      BV[fn_] = *(const short8v*)((XBUF) +                                      \
                    (wc * 64 + fn_ * 32 + l31) * 128 + kb_);                    \
  }

#define MFMA8(AV, BV)                                                           \
  {                                                                             \
    __builtin_amdgcn_s_setprio(1);                                              \
    _Pragma("unroll")                                                           \
    for (int fm_ = 0; fm_ < 4; ++fm_)                                           \
      _Pragma("unroll")                                                         \
      for (int fn_ = 0; fn_ < 2; ++fn_)                                         \
        acc[fm_][fn_] = __builtin_amdgcn_mfma_f32_32x32x16_bf16(                \
            AV[fm_], BV[fn_], acc[fm_][fn_], 0, 0, 0);                          \
    __builtin_amdgcn_s_setprio(0);                                              \
    __builtin_amdgcn_sched_barrier(0);                                          \
  }

  // ---- prologue: stage tile 0 ----
  STAGE_A(0); STAGE_X(0);
  asm volatile("s_waitcnt lgkmcnt(0)" ::: "memory");   // c2s ready

  for (int g = 0; g < NKT; ++g) {
    const char* As  = smem + (g & 1) * 32768;
    const char* Xs  = smem + 65536 + (g & 1) * 32768;
    const bool more = (g + 1 < NKT);

    if (more) {
      STAGE_A(g + 1);   // 4 new vm ops on buf (g+1)&1 (readers done: bar#2(g-1))
      asm volatile("s_waitcnt vmcnt(4)" ::: "memory");  // A(g),X(g) landed
    } else {
      asm volatile("s_waitcnt vmcnt(0)" ::: "memory");
    }
    __builtin_amdgcn_s_barrier();   // barrier#1: buf g readable everywhere
    __builtin_amdgcn_sched_barrier(0);

    // ks0 read: the single exposed-latency point of the tile
    READ_FRAGS(avE, bvE, As, Xs, 0);
    __builtin_amdgcn_sched_barrier(0);

    // phase A: read ks1, stage X(g+1), MFMA ks0
    READ_FRAGS(avO, bvO, As, Xs, 1);
    if (more) STAGE_X(g + 1);
    MFMA8(avE, bvE);

    // phase B: read ks2, MFMA ks1
    READ_FRAGS(avE, bvE, As, Xs, 2);
    MFMA8(avO, bvO);

    // phase C: read ks3, MFMA ks2
    READ_FRAGS(avO, bvO, As, Xs, 3);
    MFMA8(avE, bvE);

    // phase D: MFMA ks3
    MFMA8(avO, bvO);

    if ((g & 15) == 15) {
      // -------- selection epilogue for chunk ch (registers + c2s only) -----
      const int ch = g >> 4;
      #pragma unroll
      for (int fm = 0; fm < 4; ++fm) {
        const int rloc = ch * 256 + wr * 128 + fm * 32 + hi * 4;
        const int idb  = cb0 + ch * 256 + wr * 128 + fm * 32 + hi * 4;
        #pragma unroll
        for (int q = 0; q < 4; ++q) {
          const float4 cq = *(const float4*)&c2s[rloc + q * 8];
          #pragma unroll
          for (int fn = 0; fn < 2; ++fn) {
            #pragma unroll
            for (int r = 0; r < 4; ++r) {
              const float c2v = (r == 0) ? cq.x : (r == 1) ? cq.y : (r == 2) ? cq.z : cq.w;
              const float s = 2.f * acc[fm][fn][q * 4 + r] - c2v;
              if (s > tv[fn][KSEL - 1]) {      // strict >: ids scanned ascending
                float cv = s; int ci = idb + q * 8 + r;
                #pragma unroll
                for (int q2 = 0; q2 < KSEL; ++q2) {
                  if (cv > tv[fn][q2]) {
                    const float t0 = tv[fn][q2]; tv[fn][q2] = cv; cv = t0;
                    const int   t1 = ti[fn][q2]; ti[fn][q2] = ci; ci = t1;
                  }
                }
              }
            }
          }
        }
      }
      #pragma unroll
      for (int fm = 0; fm < 4; ++fm)
        #pragma unroll
        for (int fn = 0; fn < 2; ++fn)
          #pragma unroll
          for (int r = 0; r < 16; ++r) acc[fm][fn][r] = 0.f;
    }

    __builtin_amdgcn_s_barrier();   // barrier#2: all reads of buf g&1 done
  }

#undef READ_FRAGS
#undef MFMA8

  // -------- merge 4 lane-lists per xrow, write per-segment top-8 --------
  // stride 33 breaks the 128B-stride 32-way bank conflict (was 3.3e7 cyc)
  asm volatile("s_waitcnt vmcnt(0) lgkmcnt(0)" ::: "memory");
  __builtin_amdgcn_s_barrier();
  float* mv = (float*)smem;            // [256 xrows][33] f32 = 33.8KB
  int*   mi = (int*)(smem + 36864);
  #pragma unroll
  for (int fn = 0; fn < 2; ++fn) {
    const int xrL = wc * 64 + fn * 32 + l31;
    const int li  = wr * 2 + hi;
    #pragma unroll
    for (int q = 0; q < KSEL; ++q) {
      mv[xrL * 33 + li * 8 + q] = tv[fn][q];
      mi[xrL * 33 + li * 8 + q] = ti[fn][q];
    }
  }
  __syncthreads();
  if (t < 256) {
    float bvv[KSEL]; int bii[KSEL];
    #pragma unroll
    for (int q = 0; q < KSEL; ++q) { bvv[q] = -FLT_MAX; bii[q] = 0x7fffffff; }
    for (int c = 0; c < 32; ++c) {
      float cv = mv[t * 33 + c]; int ci = mi[t * 33 + c];
      if (cv > bvv[KSEL - 1] || (cv == bvv[KSEL - 1] && ci < bii[KSEL - 1])) {
        #pragma unroll
        for (int q = 0; q < KSEL; ++q) {
          if (cv > bvv[q] || (cv == bvv[q] && ci < bii[q])) {
            const float t0 = bvv[q]; bvv[q] = cv; cv = t0;
            const int   t1 = bii[q]; bii[q] = ci; ci = t1;
          }
        }
      }
    }
    const size_t base = ((size_t)(xbase + t) * NSPLIT + seg) * KSEL;
    #pragma unroll
    for (int q = 0; q < KSEL; ++q) { pval[base + q] = bvv[q]; pid[base + q] = bii[q]; }
  }
}

// ---------------------------------------------------------------------------
// Kernel 3: per row: merge 64 approx candidates -> top-24, exact f32 rescore
// of those 24, final top-8 (ties: lower id), gather + average.
// ---------------------------------------------------------------------------
__global__ __launch_bounds__(256)
void rescore_kernel(const float* __restrict__ X, const float* __restrict__ CB,
                    const float* __restrict__ c2g,
                    const float* __restrict__ pval, const int* __restrict__ pid,
                    float* __restrict__ out, float* __restrict__ out_ids, int nsplit) {
  const int row = blockIdx.x;
  const int t = threadIdx.x;
  __shared__ float xs[D_DIM];
  __shared__ int   scid[NC_RES];
  __shared__ float sv[NC_RES];
  __shared__ int   topid[KSEL];

  *(float4*)&xs[t * 4] = *(const float4*)(X + (size_t)row * D_DIM + t * 4);

  const int ncand = nsplit * KSEL;          // 64
  const int NC = NC_RES < ncand ? NC_RES : ncand;

  if (t < 64) {   // wave 0: merge candidates by approx score -> top-NC ids
    float v = -FLT_MAX; int idv = 0x7fffffff;
    if (t < ncand) {
      v   = pval[(size_t)row * ncand + t];
      idv = pid[(size_t)row * ncand + t];
    }
    for (int it = 0; it < NC; ++it) {
      float bv = v; int bid = idv;
      #pragma unroll
      for (int off = 32; off >= 1; off >>= 1) {
        float ov = __shfl_xor(bv, off, 64);
        int   oi = __shfl_xor(bid, off, 64);
        if (ov > bv || (ov == bv && oi < bid)) { bv = ov; bid = oi; }
      }
      if (t == 0) scid[it] = bid;
      if (idv == bid) v = -FLT_MAX;   // remove winner (ids unique)
    }
  }
  __syncthreads();

  const int w = t >> 6, ln = t & 63;
  for (int c = w; c < NC; c += 4) {
    const int id = scid[c];
    const float* cr = CB + (size_t)id * D_DIM;
    float s = 0.f;
    #pragma unroll
    for (int i = 0; i < 4; ++i) {
      const float4 cv = *(const float4*)(cr + ln * 4 + i * 256);
      const float4 xv = *(const float4*)&xs[ln * 4 + i * 256];
      s += cv.x * xv.x + cv.y * xv.y + cv.z * xv.z + cv.w * xv.w;
    }
    #pragma unroll
    for (int off = 32; off >= 1; off >>= 1) s += __shfl_xor(s, off, 64);
    if (ln == 0) sv[c] = 2.f * s - c2g[id];
  }
  __syncthreads();

  if (t == 0) {
    float bv[KSEL]; int bi[KSEL];
    #pragma unroll
    for (int q = 0; q < KSEL; ++q) { bv[q] = -FLT_MAX; bi[q] = 0x7fffffff; }
    for (int c = 0; c < NC; ++c) {
      float cv = sv[c]; int ci = scid[c];
      #pragma unroll
      for (int q = 0; q < KSEL; ++q) {
        if (cv > bv[q] || (cv == bv[q] && ci < bi[q])) {
          const float t0 = bv[q]; bv[q] = cv; cv = t0;
          const int   t1 = bi[q]; bi[q] = ci; ci = t1;
        }
      }
    }
    #pragma unroll
    for (int q = 0; q < KSEL; ++q) {
      topid[q] = bi[q];
      out_ids[(size_t)row * KSEL + q] = (float)bi[q];
    }
  }
  __syncthreads();

  float4 a = {0.f, 0.f, 0.f, 0.f};
  #pragma unroll
  for (int q = 0; q < KSEL; ++q) {
    const float4 cv = *(const float4*)(CB + (size_t)topid[q] * D_DIM + t * 4);
    a.x += cv.x; a.y += cv.y; a.z += cv.z; a.w += cv.w;
  }
  a.x *= 0.125f; a.y *= 0.125f; a.z *= 0.125f; a.w *= 0.125f;
  *(float4*)(out + (size_t)row * D_DIM + t * 4) = a;
}

// ---------------------------------------------------------------------------
extern "C" void kernel_launch(void* const* d_in, const int* in_sizes, int n_in,
                              void* d_out, int out_size, void* d_ws, size_t ws_size,
                              hipStream_t stream) {
  const float* X  = (const float*)d_in[0];
  const float* CB = (const float*)d_in[1];
  // d_in[2] = kcodes, fixed at 8 (compiled in)

  float* out     = (float*)d_out;
  float* out_ids = out + XN;

  const size_t XbB  = XN * 2;        // 16 MB
  const size_t CBbB = CBN * 2;       // 32 MB
  const size_t c2B  = C_TOTAL * 4;   // 64 KB
  const size_t pvB  = (size_t)R_TOTAL * NSPLIT * KSEL * 4;  // 2 MB

  char* p = (char*)d_ws;
  unsigned short* Xb;
  unsigned short* CBb;
  if (ws_size >= XbB + CBbB + c2B + 2 * pvB) {
    Xb  = (unsigned short*)p; p += XbB;
    CBb = (unsigned short*)p; p += CBbB;
  } else {
    // CB bf16 lives in d_out's outputs region (overwritten at the very end)
    CBb = (unsigned short*)d_out;
    Xb  = (unsigned short*)p; p += XbB;
  }
  float* c2   = (float*)p; p += c2B;
  float* pval = (float*)p; p += pvB;
  int*   pid  = (int*)p;

  hipLaunchKernelGGL(cvt_kernel, dim3((unsigned)((XN + CBN) / 8 / 256)), dim3(256), 0, stream,
                     X, CB, Xb, CBb);
  hipLaunchKernelGGL(c2_kernel, dim3(C_TOTAL / 4), dim3(256), 0, stream, CB, c2);
  hipLaunchKernelGGL(gemm_topk_kernel, dim3(32 * NSPLIT), dim3(512), 136 * 1024, stream,
                     Xb, CBb, c2, pval, pid);
  hipLaunchKernelGGL(rescore_kernel, dim3(R_TOTAL), dim3(256), 0, stream,
                     X, CB, c2, pval, pid, out, out_ids, NSPLIT);
}